// Round 2
// baseline (3991.632 us; speedup 1.0000x reference)
//
#include <hip/hip_runtime.h>

typedef short bf16x8 __attribute__((ext_vector_type(8)));
typedef unsigned short u16x8 __attribute__((ext_vector_type(8)));
typedef float f32x4 __attribute__((ext_vector_type(4)));

#define MFMA16(a, b, c) __builtin_amdgcn_mfma_f32_16x16x32_bf16((a), (b), (c), 0, 0, 0)

#define SCALEF 0.17677669529663687f  // 32^-0.5

__device__ __forceinline__ unsigned short f2bf(float f) {
  union { float f; unsigned u; } v; v.f = f;
  unsigned r = v.u + 0x7fffu + ((v.u >> 16) & 1u);  // RNE
  return (unsigned short)(r >> 16);
}

// ---------- prep kernels ----------
// Wt[n][k] = bf16(W[k][n]);  W is (K x N) row-major
__global__ __launch_bounds__(256) void transpose_cvt_k(const float* __restrict__ W,
    unsigned short* __restrict__ Wt, int K, int N) {
  int i = blockIdx.x * 256 + threadIdx.x;
  if (i >= N * K) return;
  int n = i / K, k = i - n * K;
  Wt[i] = f2bf(W[(long)k * N + n]);
}

// rpb[h][q][k] = bias_table[(dh+7)*15 + (dw+7)][h]
__global__ __launch_bounds__(256) void build_rpb_k(const float* __restrict__ bt,
    float* __restrict__ rpb) {
  int i = blockIdx.x * 256 + threadIdx.x;
  if (i >= 16 * 64 * 64) return;
  int h = i >> 12, q = (i >> 6) & 63, k = i & 63;
  int dh = (q >> 3) - (k >> 3) + 7;
  int dw = (q & 7) - (k & 7) + 7;
  rpb[i] = bt[(dh * 15 + dw) * 16 + h];
}

// ---------- full-N GEMM: C[M,BN] = A[M,512] @ Bt[BN,512]^T + bias ----------
// BM=64, BN=512*CT (entire N), BK=32. 512 threads = 8 waves; wave w owns the
// 64 x (64*CT) strip at cols w*64*CT. A is fetched from HBM exactly once.
// AT = float (cvt to bf16 while staging) or unsigned short (bf16 bits).
template <typename AT, typename OT, int CT>
__global__ __launch_bounds__(512) void gemm_wn_k(const AT* __restrict__ A,
    const unsigned short* __restrict__ Bt, const float* __restrict__ bias,
    OT* __restrict__ C, int M, int K)
{
  constexpr int BN = 512 * CT;
  constexpr int LD = 36;            // padded row (72B): ~2-way banks = free
  constexpr bool A_F32 = (sizeof(AT) == 4);
  constexpr bool O_F32 = (sizeof(OT) == 4);

  __shared__ unsigned short Asm[64][LD];
  __shared__ unsigned short Bsm[BN][LD];

  const int tid = threadIdx.x;
  const int wave = tid >> 6, lane = tid & 63;
  const int lg = lane >> 4, lc = lane & 15;
  const long rowBase = (long)blockIdx.x * 64;
  const int colBase = wave * (64 * CT);

  f32x4 acc[4][4 * CT];
#pragma unroll
  for (int i = 0; i < 4; ++i)
#pragma unroll
    for (int j = 0; j < 4 * CT; ++j)
      acc[i][j] = f32x4{0.f, 0.f, 0.f, 0.f};

  float4 aregf;           // A fp32 stage: 64 rows x 32 f32 = 512 float4
  uint2  aregh;           // A bf16 stage: 64 rows x 32 bf16 = 512 uint2
  uint4  breg[4 * CT];    // B stage: BN rows x 64B = 4*CT uint4 per thread

  const int ar = tid >> 3;          // A row (8 chunks per 32-wide row)
  const int ac = tid & 7;
  const int KT = K >> 5;            // BK=32

  auto loadA = [&](int kt) {
    if constexpr (A_F32)
      aregf = *(const float4*)(A + (rowBase + ar) * (long)K + kt * 32 + ac * 4);
    else
      aregh = *(const uint2*)(A + (rowBase + ar) * (long)K + kt * 32 + ac * 4);
  };
  auto loadB = [&](int kt) {
#pragma unroll
    for (int j = 0; j < 4 * CT; ++j) {
      int f = j * 512 + tid;
      int r = f >> 2, c = f & 3;    // 4 x 16B per 32-wide row
      breg[j] = *(const uint4*)(Bt + (long)r * K + kt * 32 + c * 8);
    }
  };
  auto storeLDS = [&]() {
    if constexpr (A_F32) {
      uint2 p;
      p.x = (unsigned)f2bf(aregf.x) | ((unsigned)f2bf(aregf.y) << 16);
      p.y = (unsigned)f2bf(aregf.z) | ((unsigned)f2bf(aregf.w) << 16);
      *(uint2*)&Asm[ar][ac * 4] = p;
    } else {
      *(uint2*)&Asm[ar][ac * 4] = aregh;
    }
#pragma unroll
    for (int j = 0; j < 4 * CT; ++j) {
      int f = j * 512 + tid;
      int r = f >> 2, c = f & 3;
      *(uint4*)&Bsm[r][c * 8] = breg[j];
    }
  };

  loadA(0); loadB(0);
  storeLDS();
  __syncthreads();

  for (int kt = 0; kt < KT; ++kt) {
    const bool more = (kt + 1 < KT);
    if (more) { loadA(kt + 1); loadB(kt + 1); }  // prefetch into regs
    bf16x8 af[4], bfr[4 * CT];
#pragma unroll
    for (int mt = 0; mt < 4; ++mt)
      af[mt] = *(const bf16x8*)&Asm[mt * 16 + lc][lg * 8];
#pragma unroll
    for (int nt = 0; nt < 4 * CT; ++nt)
      bfr[nt] = *(const bf16x8*)&Bsm[colBase + nt * 16 + lc][lg * 8];
#pragma unroll
    for (int mt = 0; mt < 4; ++mt)
#pragma unroll
      for (int nt = 0; nt < 4 * CT; ++nt)
        acc[mt][nt] = MFMA16(af[mt], bfr[nt], acc[mt][nt]);
    __syncthreads();
    if (more) { storeLDS(); __syncthreads(); }
  }

  // epilogue: bias + store
  float bv[4 * CT];
#pragma unroll
  for (int nt = 0; nt < 4 * CT; ++nt)
    bv[nt] = bias[colBase + nt * 16 + lc];
#pragma unroll
  for (int mt = 0; mt < 4; ++mt)
#pragma unroll
    for (int nt = 0; nt < 4 * CT; ++nt)
#pragma unroll
      for (int r = 0; r < 4; ++r) {
        long row = rowBase + mt * 16 + lg * 4 + r;
        int col = colBase + nt * 16 + lc;
        float v = acc[mt][nt][r] + bv[nt];
        if constexpr (O_F32) C[row * BN + col] = v;
        else                 C[row * BN + col] = f2bf(v);
      }
}

// ---------- fused window attention ----------
// grid = 4096 windows, 256 threads = 4 waves; wave w handles heads 4w..4w+3
__global__ __launch_bounds__(256) void attn_k(
    const unsigned short* __restrict__ qh,   // [B*64][512] bf16
    const unsigned short* __restrict__ kvh,  // [B*64][1024] bf16 (k | v)
    const float* __restrict__ mask,          // [64][64][64]
    const float* __restrict__ rpb,           // [16][64][64]
    unsigned short* __restrict__ x)          // [B*64][512] bf16
{
  __shared__ unsigned short P[4][64][72];    // per-wave unnormalized probs
  __shared__ unsigned short Vt[4][32][72];   // per-wave V^T [d][token]

  const int b = blockIdx.x;
  const int w = b & 63;
  const int tid = threadIdx.x;
  const int wave = tid >> 6, lane = tid & 63;
  const int lg = lane >> 4, lc = lane & 15;
  const long rowQ = (long)b * 64;

  for (int hi = 0; hi < 4; ++hi) {
    const int h = wave * 4 + hi;

    // Q as A-frags, K as B-frags (d is K-dim = 32, one MFMA step)
    bf16x8 qf[4], kf[4];
#pragma unroll
    for (int mt = 0; mt < 4; ++mt)
      qf[mt] = *(const bf16x8*)(qh + (rowQ + mt * 16 + lc) * 512 + h * 32 + lg * 8);
#pragma unroll
    for (int nt = 0; nt < 4; ++nt)
      kf[nt] = *(const bf16x8*)(kvh + (rowQ + nt * 16 + lc) * 1024 + h * 32 + lg * 8);

    f32x4 acc[4][4];
#pragma unroll
    for (int mt = 0; mt < 4; ++mt)
#pragma unroll
      for (int nt = 0; nt < 4; ++nt)
        acc[mt][nt] = f32x4{0.f, 0.f, 0.f, 0.f};
#pragma unroll
    for (int mt = 0; mt < 4; ++mt)
#pragma unroll
      for (int nt = 0; nt < 4; ++nt)
        acc[mt][nt] = MFMA16(qf[mt], kf[nt], acc[mt][nt]);

    // stage V^T: lane = token, read 32 d's, scatter to Vt[d][token]
    {
      const unsigned short* vp = kvh + (rowQ + lane) * 1024 + 512 + h * 32;
      u16x8 v0 = *(const u16x8*)(vp);
      u16x8 v1 = *(const u16x8*)(vp + 8);
      u16x8 v2 = *(const u16x8*)(vp + 16);
      u16x8 v3 = *(const u16x8*)(vp + 24);
#pragma unroll
      for (int j = 0; j < 8; ++j) {
        Vt[wave][j][lane]      = v0[j];
        Vt[wave][8 + j][lane]  = v1[j];
        Vt[wave][16 + j][lane] = v2[j];
        Vt[wave][24 + j][lane] = v3[j];
      }
    }

    // scale + rpb + mask, row softmax (rows live in 16-lane groups)
    float pden[4][4];
#pragma unroll
    for (int mt = 0; mt < 4; ++mt) {
#pragma unroll
      for (int r = 0; r < 4; ++r) {
        const int qrow = mt * 16 + lg * 4 + r;
        const float* rp = rpb + h * 4096 + qrow * 64 + lc;
        const float* mp = mask + w * 4096 + qrow * 64 + lc;
        float sc[4];
#pragma unroll
        for (int nt = 0; nt < 4; ++nt)
          sc[nt] = acc[mt][nt][r] * SCALEF + rp[nt * 16] + mp[nt * 16];
        float mx = fmaxf(fmaxf(sc[0], sc[1]), fmaxf(sc[2], sc[3]));
        mx = fmaxf(mx, __shfl_xor(mx, 1));
        mx = fmaxf(mx, __shfl_xor(mx, 2));
        mx = fmaxf(mx, __shfl_xor(mx, 4));
        mx = fmaxf(mx, __shfl_xor(mx, 8));
        float s = 0.f;
#pragma unroll
        for (int nt = 0; nt < 4; ++nt) { sc[nt] = __expf(sc[nt] - mx); s += sc[nt]; }
        s += __shfl_xor(s, 1);
        s += __shfl_xor(s, 2);
        s += __shfl_xor(s, 4);
        s += __shfl_xor(s, 8);
        pden[mt][r] = 1.f / s;
#pragma unroll
        for (int nt = 0; nt < 4; ++nt)
          P[wave][qrow][nt * 16 + lc] = f2bf(sc[nt]);
      }
    }
    __syncthreads();

    // PV: x[q][d] = sum_tok P[q][tok] * V[tok][d]
    f32x4 xacc[4][2];
#pragma unroll
    for (int mt = 0; mt < 4; ++mt)
#pragma unroll
      for (int nt = 0; nt < 2; ++nt)
        xacc[mt][nt] = f32x4{0.f, 0.f, 0.f, 0.f};
#pragma unroll
    for (int ks = 0; ks < 2; ++ks) {
      bf16x8 pa[4], vb[2];
#pragma unroll
      for (int mt = 0; mt < 4; ++mt)
        pa[mt] = *(const bf16x8*)&P[wave][mt * 16 + lc][ks * 32 + lg * 8];
#pragma unroll
      for (int nt = 0; nt < 2; ++nt)
        vb[nt] = *(const bf16x8*)&Vt[wave][nt * 16 + lc][ks * 32 + lg * 8];
#pragma unroll
      for (int mt = 0; mt < 4; ++mt)
#pragma unroll
        for (int nt = 0; nt < 2; ++nt)
          xacc[mt][nt] = MFMA16(pa[mt], vb[nt], xacc[mt][nt]);
    }

    // normalize + store
#pragma unroll
    for (int mt = 0; mt < 4; ++mt)
#pragma unroll
      for (int nt = 0; nt < 2; ++nt)
#pragma unroll
        for (int r = 0; r < 4; ++r) {
          const int qrow = mt * 16 + lg * 4 + r;
          x[(rowQ + qrow) * 512 + h * 32 + nt * 16 + lc] =
              f2bf(xacc[mt][nt][r] * pden[mt][r]);
        }
    __syncthreads();
  }
}

extern "C" void kernel_launch(void* const* d_in, const int* in_sizes, int n_in,
                              void* d_out, int out_size, void* d_ws, size_t ws_size,
                              hipStream_t stream) {
  const float* q    = (const float*)d_in[0];
  const float* kv   = (const float*)d_in[1];
  const float* mask = (const float*)d_in[2];
  const float* Wq   = (const float*)d_in[3];
  const float* bq   = (const float*)d_in[4];
  const float* Wkv  = (const float*)d_in[5];
  const float* bkv  = (const float*)d_in[6];
  const float* btab = (const float*)d_in[7];
  const float* Wp   = (const float*)d_in[8];
  const float* bp   = (const float*)d_in[9];
  float* out = (float*)d_out;

  const int M = 4096 * 64;  // 262144 rows

  char* ws = (char*)d_ws;
  const size_t OFF_QH  = 0;                                // 256 MB
  const size_t OFF_KVH = OFF_QH + (size_t)M * 512 * 2;     // 512 MB
  const size_t OFF_X   = OFF_KVH + (size_t)M * 1024 * 2;   // 256 MB
  const size_t OFF_WQT = OFF_X + (size_t)M * 512 * 2;
  const size_t OFF_WKVT = OFF_WQT + 512 * 512 * 2;
  const size_t OFF_WPT  = OFF_WKVT + 1024 * 512 * 2;
  const size_t OFF_RPB  = OFF_WPT + 512 * 512 * 2;

  unsigned short* qh    = (unsigned short*)(ws + OFF_QH);
  unsigned short* kvh   = (unsigned short*)(ws + OFF_KVH);
  unsigned short* xb    = (unsigned short*)(ws + OFF_X);
  unsigned short* Wq_t  = (unsigned short*)(ws + OFF_WQT);
  unsigned short* Wkv_t = (unsigned short*)(ws + OFF_WKVT);
  unsigned short* Wp_t  = (unsigned short*)(ws + OFF_WPT);
  float* rpbf           = (float*)(ws + OFF_RPB);

  transpose_cvt_k<<<(512 * 512 + 255) / 256, 256, 0, stream>>>(Wq, Wq_t, 512, 512);
  transpose_cvt_k<<<(512 * 1024 + 255) / 256, 256, 0, stream>>>(Wkv, Wkv_t, 512, 1024);
  transpose_cvt_k<<<(512 * 512 + 255) / 256, 256, 0, stream>>>(Wp, Wp_t, 512, 512);
  build_rpb_k<<<(16 * 64 * 64 + 255) / 256, 256, 0, stream>>>(btab, rpbf);

  gemm_wn_k<float, unsigned short, 1><<<M / 64, 512, 0, stream>>>(
      q, Wq_t, bq, qh, M, 512);
  gemm_wn_k<float, unsigned short, 2><<<M / 64, 512, 0, stream>>>(
      kv, Wkv_t, bkv, kvh, M, 512);

  attn_k<<<4096, 256, 0, stream>>>(qh, kvh, mask, rpbf, xb);

  gemm_wn_k<unsigned short, float, 1><<<M / 64, 512, 0, stream>>>(
      xb, Wp_t, bp, out, M, 512);

  (void)in_sizes; (void)n_in; (void)out_size; (void)ws_size;
}

// Round 3
// 2864.166 us; speedup vs baseline: 1.3936x; 1.3936x over previous
//
#include <hip/hip_runtime.h>

typedef short bf16x8 __attribute__((ext_vector_type(8)));
typedef unsigned short u16x8 __attribute__((ext_vector_type(8)));
typedef float f32x4 __attribute__((ext_vector_type(4)));

#define MFMA16(a, b, c) __builtin_amdgcn_mfma_f32_16x16x32_bf16((a), (b), (c), 0, 0, 0)

#define SCALEF 0.17677669529663687f  // 32^-0.5

__device__ __forceinline__ unsigned short f2bf(float f) {
  union { float f; unsigned u; } v; v.f = f;
  unsigned r = v.u + 0x7fffu + ((v.u >> 16) & 1u);  // RNE
  return (unsigned short)(r >> 16);
}

// ---------- prep kernels ----------
__global__ __launch_bounds__(256) void transpose_cvt_k(const float* __restrict__ W,
    unsigned short* __restrict__ Wt, int K, int N) {
  int i = blockIdx.x * 256 + threadIdx.x;
  if (i >= N * K) return;
  int n = i / K, k = i - n * K;
  Wt[i] = f2bf(W[(long)k * N + n]);
}

__global__ __launch_bounds__(256) void build_rpb_k(const float* __restrict__ bt,
    float* __restrict__ rpb) {
  int i = blockIdx.x * 256 + threadIdx.x;
  if (i >= 16 * 64 * 64) return;
  int h = i >> 12, q = (i >> 6) & 63, k = i & 63;
  int dh = (q >> 3) - (k >> 3) + 7;
  int dw = (q & 7) - (k & 7) + 7;
  rpb[i] = bt[(dh * 15 + dw) * 16 + h];
}

// ---------- GEMM: C[M,N] = A[M,K] @ Bt[N,K]^T + bias ----------
// 128x128 tile, BK=64, 256 threads (4 waves 2x2). XCD-swizzled blockIdx so the
// tn blocks sharing an A-panel land on ONE XCD (A fetched from HBM ~once).
// Epilogue stages the tile in LDS and writes full contiguous segments.
template <typename AT, typename OT>
__global__ __launch_bounds__(256) void gemm_k(const AT* __restrict__ A,
    const unsigned short* __restrict__ Bt, const float* __restrict__ bias,
    OT* __restrict__ C, int M, int N, int K)
{
  constexpr bool A_F32 = (sizeof(AT) == 4);
  constexpr bool O_F32 = (sizeof(OT) == 4);

  const int tn = N >> 7;
  const int nbm = M >> 7;                 // 2048, divisible by 8
  // XCD-aware swizzle: hardware XCD = blockIdx % 8 (round-robin). Blocks with
  // the same bm (A-panel sharers) are 8 apart -> same XCD, adjacent in time.
  {
  }
  const int g = blockIdx.x;
  const int xcd = g & 7;
  const int s = g >> 3;
  const int bm = xcd * (nbm >> 3) + (s / tn);
  const int bn = s - (s / tn) * tn;

  const int tid = threadIdx.x;
  const int wave = tid >> 6, lane = tid & 63;
  const int wr = wave >> 1, wc = wave & 1;
  const int lg = lane >> 4, lc = lane & 15;

  __shared__ unsigned short SMEM[2][128][72];   // 36864 B
  unsigned short (*Asm)[72] = SMEM[0];
  unsigned short (*Bsm)[72] = SMEM[1];

  f32x4 acc[4][4];
#pragma unroll
  for (int i = 0; i < 4; ++i)
#pragma unroll
    for (int j = 0; j < 4; ++j)
      acc[i][j] = f32x4{0.f, 0.f, 0.f, 0.f};

  float4 aregf[8];
  uint4 aregh[4];
  uint4 breg[4];

  const long rowBase = (long)bm * 128;
  const int colBase = bn * 128;
  const int KT = K >> 6;

  auto loadA = [&](int kt) {
    if constexpr (A_F32) {
#pragma unroll
      for (int j = 0; j < 8; ++j) {
        int f = j * 256 + tid;
        int r = f >> 4, c4 = f & 15;
        aregf[j] = *(const float4*)(A + (rowBase + r) * (long)K + kt * 64 + c4 * 4);
      }
    } else {
#pragma unroll
      for (int j = 0; j < 4; ++j) {
        int f = j * 256 + tid;
        int r = f >> 3, c8 = f & 7;
        aregh[j] = *(const uint4*)(A + (rowBase + r) * (long)K + kt * 64 + c8 * 8);
      }
    }
  };
  auto loadB = [&](int kt) {
#pragma unroll
    for (int j = 0; j < 4; ++j) {
      int f = j * 256 + tid;
      int r = f >> 3, c8 = f & 7;
      breg[j] = *(const uint4*)(Bt + (long)(colBase + r) * K + kt * 64 + c8 * 8);
    }
  };
  auto storeLDS = [&]() {
    if constexpr (A_F32) {
#pragma unroll
      for (int j = 0; j < 8; ++j) {
        int f = j * 256 + tid;
        int r = f >> 4, c4 = f & 15;
        uint2 p;
        p.x = (unsigned)f2bf(aregf[j].x) | ((unsigned)f2bf(aregf[j].y) << 16);
        p.y = (unsigned)f2bf(aregf[j].z) | ((unsigned)f2bf(aregf[j].w) << 16);
        *(uint2*)&Asm[r][c4 * 4] = p;
      }
    } else {
#pragma unroll
      for (int j = 0; j < 4; ++j) {
        int f = j * 256 + tid;
        int r = f >> 3, c8 = f & 7;
        *(uint4*)&Asm[r][c8 * 8] = aregh[j];
      }
    }
#pragma unroll
    for (int j = 0; j < 4; ++j) {
      int f = j * 256 + tid;
      int r = f >> 3, c8 = f & 7;
      *(uint4*)&Bsm[r][c8 * 8] = breg[j];
    }
  };

  loadA(0); loadB(0);
  storeLDS();
  __syncthreads();

  for (int kt = 0; kt < KT; ++kt) {
    const bool more = (kt + 1 < KT);
    if (more) { loadA(kt + 1); loadB(kt + 1); }
#pragma unroll
    for (int ks = 0; ks < 2; ++ks) {
      bf16x8 af[4], bfr[4];
#pragma unroll
      for (int mt = 0; mt < 4; ++mt)
        af[mt] = *(const bf16x8*)&Asm[wr * 64 + mt * 16 + lc][ks * 32 + lg * 8];
#pragma unroll
      for (int nt = 0; nt < 4; ++nt)
        bfr[nt] = *(const bf16x8*)&Bsm[wc * 64 + nt * 16 + lc][ks * 32 + lg * 8];
#pragma unroll
      for (int mt = 0; mt < 4; ++mt)
#pragma unroll
        for (int nt = 0; nt < 4; ++nt)
          acc[mt][nt] = MFMA16(af[mt], bfr[nt], acc[mt][nt]);
    }
    __syncthreads();
    if (more) { storeLDS(); __syncthreads(); }
  }
  // (loop ends with a barrier after the last fragment reads -> SMEM reusable)

  float bv[4];
#pragma unroll
  for (int nt = 0; nt < 4; ++nt)
    bv[nt] = bias[colBase + wc * 64 + nt * 16 + lc];

  unsigned short* S = &SMEM[0][0][0];     // 18432 shorts / 36864 B scratch

  if constexpr (!O_F32) {
    // bf16 out: stage [128][136] shorts (272 B pitch, 16B-aligned), then
    // write 16 B per lane, 4 full 256 B rows per wave instruction.
    constexpr int EP = 136;
#pragma unroll
    for (int mt = 0; mt < 4; ++mt)
#pragma unroll
      for (int nt = 0; nt < 4; ++nt)
#pragma unroll
        for (int r = 0; r < 4; ++r) {
          int lr = wr * 64 + mt * 16 + lg * 4 + r;
          int col = wc * 64 + nt * 16 + lc;
          S[lr * EP + col] = f2bf(acc[mt][nt][r] + bv[nt]);
        }
    __syncthreads();
#pragma unroll
    for (int p = 0; p < 8; ++p) {
      int ch = p * 256 + tid;              // 128 rows x 16 chunks(16B)
      int row = ch >> 4, c = ch & 15;
      uint4 v = *(const uint4*)&S[row * EP + c * 8];
      *(uint4*)((unsigned short*)C + (rowBase + row) * N + colBase + c * 8) = v;
    }
  } else {
    // fp32 out: stage 64-row halves as [64][132] f32 (528 B pitch).
    float* Sf = (float*)S;
    constexpr int EPF = 132;
#pragma unroll
    for (int h = 0; h < 2; ++h) {
      if (wr == h) {
#pragma unroll
        for (int mt = 0; mt < 4; ++mt)
#pragma unroll
          for (int nt = 0; nt < 4; ++nt)
#pragma unroll
            for (int r = 0; r < 4; ++r) {
              int lr = mt * 16 + lg * 4 + r;
              int col = wc * 64 + nt * 16 + lc;
              Sf[lr * EPF + col] = acc[mt][nt][r] + bv[nt];
            }
      }
      __syncthreads();
#pragma unroll
      for (int p = 0; p < 8; ++p) {
        int ch = p * 256 + tid;            // 64 rows x 32 chunks(16B)
        int row = ch >> 5, c = ch & 31;
        float4 v = *(const float4*)&Sf[row * EPF + c * 4];
        *(float4*)((float*)C + (rowBase + h * 64 + row) * N + colBase + c * 4) = v;
      }
      __syncthreads();
    }
  }
}

// ---------- fused window attention ----------
__global__ __launch_bounds__(256) void attn_k(
    const unsigned short* __restrict__ qh,   // [B*64][512] bf16
    const unsigned short* __restrict__ kvh,  // [B*64][1024] bf16 (k | v)
    const float* __restrict__ mask,          // [64][64][64]
    const float* __restrict__ rpb,           // [16][64][64]
    unsigned short* __restrict__ x)          // [B*64][512] bf16
{
  __shared__ unsigned short P[4][64][72];
  __shared__ unsigned short Vt[4][32][72];

  const int b = blockIdx.x;
  const int w = b & 63;
  const int tid = threadIdx.x;
  const int wave = tid >> 6, lane = tid & 63;
  const int lg = lane >> 4, lc = lane & 15;
  const long rowQ = (long)b * 64;

  for (int hi = 0; hi < 4; ++hi) {
    const int h = wave * 4 + hi;

    bf16x8 qf[4], kf[4];
#pragma unroll
    for (int mt = 0; mt < 4; ++mt)
      qf[mt] = *(const bf16x8*)(qh + (rowQ + mt * 16 + lc) * 512 + h * 32 + lg * 8);
#pragma unroll
    for (int nt = 0; nt < 4; ++nt)
      kf[nt] = *(const bf16x8*)(kvh + (rowQ + nt * 16 + lc) * 1024 + h * 32 + lg * 8);

    f32x4 acc[4][4];
#pragma unroll
    for (int mt = 0; mt < 4; ++mt)
#pragma unroll
      for (int nt = 0; nt < 4; ++nt)
        acc[mt][nt] = f32x4{0.f, 0.f, 0.f, 0.f};
#pragma unroll
    for (int mt = 0; mt < 4; ++mt)
#pragma unroll
      for (int nt = 0; nt < 4; ++nt)
        acc[mt][nt] = MFMA16(qf[mt], kf[nt], acc[mt][nt]);

    {
      const unsigned short* vp = kvh + (rowQ + lane) * 1024 + 512 + h * 32;
      u16x8 v0 = *(const u16x8*)(vp);
      u16x8 v1 = *(const u16x8*)(vp + 8);
      u16x8 v2 = *(const u16x8*)(vp + 16);
      u16x8 v3 = *(const u16x8*)(vp + 24);
#pragma unroll
      for (int j = 0; j < 8; ++j) {
        Vt[wave][j][lane]      = v0[j];
        Vt[wave][8 + j][lane]  = v1[j];
        Vt[wave][16 + j][lane] = v2[j];
        Vt[wave][24 + j][lane] = v3[j];
      }
    }

    float pden[4][4];
#pragma unroll
    for (int mt = 0; mt < 4; ++mt) {
#pragma unroll
      for (int r = 0; r < 4; ++r) {
        const int qrow = mt * 16 + lg * 4 + r;
        const float* rp = rpb + h * 4096 + qrow * 64 + lc;
        const float* mp = mask + w * 4096 + qrow * 64 + lc;
        float sc[4];
#pragma unroll
        for (int nt = 0; nt < 4; ++nt)
          sc[nt] = acc[mt][nt][r] * SCALEF + rp[nt * 16] + mp[nt * 16];
        float mx = fmaxf(fmaxf(sc[0], sc[1]), fmaxf(sc[2], sc[3]));
        mx = fmaxf(mx, __shfl_xor(mx, 1));
        mx = fmaxf(mx, __shfl_xor(mx, 2));
        mx = fmaxf(mx, __shfl_xor(mx, 4));
        mx = fmaxf(mx, __shfl_xor(mx, 8));
        float s = 0.f;
#pragma unroll
        for (int nt = 0; nt < 4; ++nt) { sc[nt] = __expf(sc[nt] - mx); s += sc[nt]; }
        s += __shfl_xor(s, 1);
        s += __shfl_xor(s, 2);
        s += __shfl_xor(s, 4);
        s += __shfl_xor(s, 8);
        pden[mt][r] = 1.f / s;
#pragma unroll
        for (int nt = 0; nt < 4; ++nt)
          P[wave][qrow][nt * 16 + lc] = f2bf(sc[nt]);
      }
    }
    __syncthreads();

    f32x4 xacc[4][2];
#pragma unroll
    for (int mt = 0; mt < 4; ++mt)
#pragma unroll
      for (int nt = 0; nt < 2; ++nt)
        xacc[mt][nt] = f32x4{0.f, 0.f, 0.f, 0.f};
#pragma unroll
    for (int ks = 0; ks < 2; ++ks) {
      bf16x8 pa[4], vb[2];
#pragma unroll
      for (int mt = 0; mt < 4; ++mt)
        pa[mt] = *(const bf16x8*)&P[wave][mt * 16 + lc][ks * 32 + lg * 8];
#pragma unroll
      for (int nt = 0; nt < 2; ++nt)
        vb[nt] = *(const bf16x8*)&Vt[wave][nt * 16 + lc][ks * 32 + lg * 8];
#pragma unroll
      for (int mt = 0; mt < 4; ++mt)
#pragma unroll
        for (int nt = 0; nt < 2; ++nt)
          xacc[mt][nt] = MFMA16(pa[mt], vb[nt], xacc[mt][nt]);
    }

#pragma unroll
    for (int mt = 0; mt < 4; ++mt)
#pragma unroll
      for (int nt = 0; nt < 2; ++nt)
#pragma unroll
        for (int r = 0; r < 4; ++r) {
          const int qrow = mt * 16 + lg * 4 + r;
          x[(rowQ + qrow) * 512 + h * 32 + nt * 16 + lc] =
              f2bf(xacc[mt][nt][r] * pden[mt][r]);
        }
    __syncthreads();
  }
}

extern "C" void kernel_launch(void* const* d_in, const int* in_sizes, int n_in,
                              void* d_out, int out_size, void* d_ws, size_t ws_size,
                              hipStream_t stream) {
  const float* q    = (const float*)d_in[0];
  const float* kv   = (const float*)d_in[1];
  const float* mask = (const float*)d_in[2];
  const float* Wq   = (const float*)d_in[3];
  const float* bq   = (const float*)d_in[4];
  const float* Wkv  = (const float*)d_in[5];
  const float* bkv  = (const float*)d_in[6];
  const float* btab = (const float*)d_in[7];
  const float* Wp   = (const float*)d_in[8];
  const float* bp   = (const float*)d_in[9];
  float* out = (float*)d_out;

  const int M = 4096 * 64;  // 262144 rows

  char* ws = (char*)d_ws;
  const size_t OFF_QH  = 0;
  const size_t OFF_KVH = OFF_QH + (size_t)M * 512 * 2;
  const size_t OFF_X   = OFF_KVH + (size_t)M * 1024 * 2;
  const size_t OFF_WQT = OFF_X + (size_t)M * 512 * 2;
  const size_t OFF_WKVT = OFF_WQT + 512 * 512 * 2;
  const size_t OFF_WPT  = OFF_WKVT + 1024 * 512 * 2;
  const size_t OFF_RPB  = OFF_WPT + 512 * 512 * 2;

  unsigned short* qh    = (unsigned short*)(ws + OFF_QH);
  unsigned short* kvh   = (unsigned short*)(ws + OFF_KVH);
  unsigned short* xb    = (unsigned short*)(ws + OFF_X);
  unsigned short* Wq_t  = (unsigned short*)(ws + OFF_WQT);
  unsigned short* Wkv_t = (unsigned short*)(ws + OFF_WKVT);
  unsigned short* Wp_t  = (unsigned short*)(ws + OFF_WPT);
  float* rpbf           = (float*)(ws + OFF_RPB);

  transpose_cvt_k<<<(512 * 512 + 255) / 256, 256, 0, stream>>>(Wq, Wq_t, 512, 512);
  transpose_cvt_k<<<(512 * 1024 + 255) / 256, 256, 0, stream>>>(Wkv, Wkv_t, 512, 1024);
  transpose_cvt_k<<<(512 * 512 + 255) / 256, 256, 0, stream>>>(Wp, Wp_t, 512, 512);
  build_rpb_k<<<(16 * 64 * 64 + 255) / 256, 256, 0, stream>>>(btab, rpbf);

  gemm_k<float, unsigned short><<<(M / 128) * (512 / 128), 256, 0, stream>>>(
      q, Wq_t, bq, qh, M, 512, 512);
  gemm_k<float, unsigned short><<<(M / 128) * (1024 / 128), 256, 0, stream>>>(
      kv, Wkv_t, bkv, kvh, M, 1024, 512);

  attn_k<<<4096, 256, 0, stream>>>(qh, kvh, mask, rpbf, xb);

  gemm_k<unsigned short, float><<<(M / 128) * (512 / 128), 256, 0, stream>>>(
      xb, Wp_t, bp, out, M, 512, 512);

  (void)in_sizes; (void)n_in; (void)out_size; (void)ws_size;
}

// Round 4
// 2676.576 us; speedup vs baseline: 1.4913x; 1.0701x over previous
//
#include <hip/hip_runtime.h>

typedef short bf16x8 __attribute__((ext_vector_type(8)));
typedef unsigned short u16x8 __attribute__((ext_vector_type(8)));
typedef float f32x4 __attribute__((ext_vector_type(4)));

#define MFMA16(a, b, c) __builtin_amdgcn_mfma_f32_16x16x32_bf16((a), (b), (c), 0, 0, 0)

#define SCALEF 0.17677669529663687f  // 32^-0.5

__device__ __forceinline__ unsigned short f2bf(float f) {
  union { float f; unsigned u; } v; v.f = f;
  unsigned r = v.u + 0x7fffu + ((v.u >> 16) & 1u);  // RNE
  return (unsigned short)(r >> 16);
}

__device__ __forceinline__ void gl_lds16(const void* g, void* l) {
  __builtin_amdgcn_global_load_lds(
      (const __attribute__((address_space(1))) void*)g,
      (__attribute__((address_space(3))) void*)l, 16, 0, 0);
}

// ---------- prep kernels ----------
__global__ __launch_bounds__(256) void transpose_cvt_k(const float* __restrict__ W,
    unsigned short* __restrict__ Wt, int K, int N) {
  int i = blockIdx.x * 256 + threadIdx.x;
  if (i >= N * K) return;
  int n = i / K, k = i - n * K;
  Wt[i] = f2bf(W[(long)k * N + n]);
}

__global__ __launch_bounds__(256) void build_rpb_k(const float* __restrict__ bt,
    float* __restrict__ rpb) {
  int i = blockIdx.x * 256 + threadIdx.x;
  if (i >= 16 * 64 * 64) return;
  int h = i >> 12, q = (i >> 6) & 63, k = i & 63;
  int dh = (q >> 3) - (k >> 3) + 7;
  int dw = (q & 7) - (k & 7) + 7;
  rpb[i] = bt[(dh * 15 + dw) * 16 + h];
}

// ---------- GEMM body: C[M,N] = A[M,K] @ Bt[N,K]^T + bias ----------
// 128x128 tile, BK=64, 256 threads (4 waves 2x2), XCD-swizzled blockIdx.
// LDS tiles are [128][8 chunks of 16B], XOR-swizzled: chunk' = chunk ^ (row&7).
// bf16 operands stream via global_load_lds (linear LDS dest, pre-swizzled
// per-lane global source); fp32 A is reg-staged (loads issued before MFMA
// phase), converted, and ds_written to the same swizzled layout.
template <typename AT, typename OT>
__device__ __forceinline__ void gemm_body(const AT* __restrict__ A,
    const unsigned short* __restrict__ Bt, const float* __restrict__ bias,
    OT* __restrict__ C, int M, int N, int K)
{
  constexpr bool A_F32 = (sizeof(AT) == 4);
  constexpr bool O_F32 = (sizeof(OT) == 4);

  __shared__ __align__(16) char smem[32768];
  unsigned short* Asm = (unsigned short*)smem;   // [128][64] swizzled, 16 KB
  unsigned short* Bsm = Asm + 8192;              // [128][64] swizzled, 16 KB

  const int tn = N >> 7;
  const int nbm = M >> 7;                        // 2048, divisible by 8
  const int g = blockIdx.x;
  const int xcd = g & 7;                         // hw XCD = blockIdx % 8
  const int s = g >> 3;
  const int bm = xcd * (nbm >> 3) + (s / tn);    // A-panel sharers on one XCD
  const int bn = s - (s / tn) * tn;

  const int tid = threadIdx.x;
  const int wave = tid >> 6, lane = tid & 63;
  const int wr = wave >> 1, wc = wave & 1;
  const int lg = lane >> 4, lc = lane & 15;

  const long rowBase = (long)bm * 128;
  const int colBase = bn * 128;
  const int KT = K >> 6;

  f32x4 acc[4][4];
#pragma unroll
  for (int i = 0; i < 4; ++i)
#pragma unroll
    for (int j = 0; j < 4; ++j)
      acc[i][j] = f32x4{0.f, 0.f, 0.f, 0.f};

  // lds-direct staging lane geometry (16B per lane per issue)
  const int blr = lane >> 3, blcc = lane & 7;    // row-in-8, chunk
  const int bsw = blcc ^ blr;                    // swizzled source chunk
  // fp32 A reg staging geometry (32B per thread per pass)
  const int sr = tid >> 3, scc = tid & 7;        // row-in-32, chunk
  const int asw = scc ^ (sr & 7);

  float4 areg[8];

  auto issueB = [&](int kt) {
#pragma unroll
    for (int j = 0; j < 4; ++j) {
      int r = j * 32 + wave * 8 + blr;
      gl_lds16(Bt + (long)(colBase + r) * K + kt * 64 + bsw * 8,
               Bsm + (j * 4 + wave) * 512);
    }
  };
  auto issueA_lds = [&](int kt) {   // bf16 A
#pragma unroll
    for (int j = 0; j < 4; ++j) {
      int r = j * 32 + wave * 8 + blr;
      gl_lds16((const unsigned short*)A + (rowBase + r) * (long)K + kt * 64 + bsw * 8,
               Asm + (j * 4 + wave) * 512);
    }
  };
  auto loadAreg = [&](int kt) {     // fp32 A: issue early, consumed after barrier
#pragma unroll
    for (int p = 0; p < 4; ++p) {
      const float* src = (const float*)A + (rowBase + p * 32 + sr) * (long)K + kt * 64 + scc * 8;
      areg[2 * p]     = *(const float4*)src;
      areg[2 * p + 1] = *(const float4*)(src + 4);
    }
  };
  auto writeAreg = [&]() {
#pragma unroll
    for (int p = 0; p < 4; ++p) {
      uint4 pk;
      pk.x = (unsigned)f2bf(areg[2 * p].x)     | ((unsigned)f2bf(areg[2 * p].y) << 16);
      pk.y = (unsigned)f2bf(areg[2 * p].z)     | ((unsigned)f2bf(areg[2 * p].w) << 16);
      pk.z = (unsigned)f2bf(areg[2 * p + 1].x) | ((unsigned)f2bf(areg[2 * p + 1].y) << 16);
      pk.w = (unsigned)f2bf(areg[2 * p + 1].z) | ((unsigned)f2bf(areg[2 * p + 1].w) << 16);
      *(uint4*)(Asm + (p * 32 + sr) * 64 + asw * 8) = pk;
    }
  };
  auto compute = [&]() {
#pragma unroll
    for (int ks = 0; ks < 2; ++ks) {
      const int ca = (ks * 4 + lg) ^ (lc & 7);   // swizzled read chunk
      bf16x8 af[4], bfr[4];
#pragma unroll
      for (int mt = 0; mt < 4; ++mt)
        af[mt] = *(const bf16x8*)(Asm + (wr * 64 + mt * 16 + lc) * 64 + ca * 8);
#pragma unroll
      for (int nt = 0; nt < 4; ++nt)
        bfr[nt] = *(const bf16x8*)(Bsm + (wc * 64 + nt * 16 + lc) * 64 + ca * 8);
#pragma unroll
      for (int mt = 0; mt < 4; ++mt)
#pragma unroll
        for (int nt = 0; nt < 4; ++nt)
          acc[mt][nt] = MFMA16(af[mt], bfr[nt], acc[mt][nt]);
    }
  };

  // prologue
  if constexpr (A_F32) { loadAreg(0); writeAreg(); }
  else                 { issueA_lds(0); }
  issueB(0);
  __syncthreads();

  for (int kt = 0; kt < KT; ++kt) {
    const bool more = (kt + 1 < KT);
    if (more) { if constexpr (A_F32) loadAreg(kt + 1); }  // hide under MFMA
    compute();
    __syncthreads();
    if (more) {
      if constexpr (A_F32) writeAreg();
      else                 issueA_lds(kt + 1);
      issueB(kt + 1);
      __syncthreads();
    }
  }

  // epilogue: bias + LDS-staged contiguous stores (reuse tile LDS, 64-row halves)
  float bv[4];
#pragma unroll
  for (int nt = 0; nt < 4; ++nt)
    bv[nt] = bias[colBase + wc * 64 + nt * 16 + lc];

  if constexpr (O_F32) {
    float* Sf = (float*)smem;                    // [64][128] f32
#pragma unroll
    for (int h = 0; h < 2; ++h) {
      if (wr == h) {
#pragma unroll
        for (int mt = 0; mt < 4; ++mt)
#pragma unroll
          for (int nt = 0; nt < 4; ++nt)
#pragma unroll
            for (int r = 0; r < 4; ++r)
              Sf[(mt * 16 + lg * 4 + r) * 128 + wc * 64 + nt * 16 + lc] =
                  acc[mt][nt][r] + bv[nt];
      }
      __syncthreads();
#pragma unroll
      for (int p = 0; p < 8; ++p) {
        int ch = p * 256 + tid, row = ch >> 5, c = ch & 31;
        *(float4*)((float*)C + (rowBase + h * 64 + row) * N + colBase + c * 4) =
            *(const float4*)(Sf + row * 128 + c * 4);
      }
      __syncthreads();
    }
  } else {
    unsigned short* Su = (unsigned short*)smem;  // [64][128] bf16
#pragma unroll
    for (int h = 0; h < 2; ++h) {
      if (wr == h) {
#pragma unroll
        for (int mt = 0; mt < 4; ++mt)
#pragma unroll
          for (int nt = 0; nt < 4; ++nt)
#pragma unroll
            for (int r = 0; r < 4; ++r)
              Su[(mt * 16 + lg * 4 + r) * 128 + wc * 64 + nt * 16 + lc] =
                  f2bf(acc[mt][nt][r] + bv[nt]);
      }
      __syncthreads();
#pragma unroll
      for (int p = 0; p < 4; ++p) {
        int ch = p * 256 + tid, row = ch >> 4, c = ch & 15;
        *(uint4*)((unsigned short*)C + (rowBase + h * 64 + row) * N + colBase + c * 8) =
            *(const uint4*)(Su + row * 128 + c * 8);
      }
      __syncthreads();
    }
  }
}

__global__ __launch_bounds__(256, 3) void gemm_q_k(const float* __restrict__ A,
    const unsigned short* __restrict__ Bt, const float* __restrict__ bias,
    unsigned short* __restrict__ C, int M, int N, int K) {
  gemm_body<float, unsigned short>(A, Bt, bias, C, M, N, K);
}
__global__ __launch_bounds__(256, 3) void gemm_kv_k(const float* __restrict__ A,
    const unsigned short* __restrict__ Bt, const float* __restrict__ bias,
    unsigned short* __restrict__ C, int M, int N, int K) {
  gemm_body<float, unsigned short>(A, Bt, bias, C, M, N, K);
}
__global__ __launch_bounds__(256, 3) void gemm_out_k(const unsigned short* __restrict__ A,
    const unsigned short* __restrict__ Bt, const float* __restrict__ bias,
    float* __restrict__ C, int M, int N, int K) {
  gemm_body<unsigned short, float>(A, Bt, bias, C, M, N, K);
}

// ---------- fused window attention ----------
// grid = 4096 windows, 4 waves; wave w handles heads 4w..4w+3.
// P/Vt are wave-private LDS -> NO block barriers needed (wave-internal
// lgkmcnt ordering suffices); waves run unlocked.
__global__ __launch_bounds__(256) void attn_k(
    const unsigned short* __restrict__ qh,   // [B*64][512] bf16
    const unsigned short* __restrict__ kvh,  // [B*64][1024] bf16 (k | v)
    const float* __restrict__ mask,          // [64][64][64]
    const float* __restrict__ rpb,           // [16][64][64]
    unsigned short* __restrict__ x)          // [B*64][512] bf16
{
  __shared__ unsigned short P[4][64][72];
  __shared__ unsigned short Vt[4][32][72];

  const int b = blockIdx.x;
  const int w = b & 63;
  const int tid = threadIdx.x;
  const int wave = tid >> 6, lane = tid & 63;
  const int lg = lane >> 4, lc = lane & 15;
  const long rowQ = (long)b * 64;

  for (int hi = 0; hi < 4; ++hi) {
    const int h = wave * 4 + hi;

    bf16x8 qf[4], kf[4];
#pragma unroll
    for (int mt = 0; mt < 4; ++mt)
      qf[mt] = *(const bf16x8*)(qh + (rowQ + mt * 16 + lc) * 512 + h * 32 + lg * 8);
#pragma unroll
    for (int nt = 0; nt < 4; ++nt)
      kf[nt] = *(const bf16x8*)(kvh + (rowQ + nt * 16 + lc) * 1024 + h * 32 + lg * 8);

    f32x4 acc[4][4];
#pragma unroll
    for (int mt = 0; mt < 4; ++mt)
#pragma unroll
      for (int nt = 0; nt < 4; ++nt)
        acc[mt][nt] = f32x4{0.f, 0.f, 0.f, 0.f};
#pragma unroll
    for (int mt = 0; mt < 4; ++mt)
#pragma unroll
      for (int nt = 0; nt < 4; ++nt)
        acc[mt][nt] = MFMA16(qf[mt], kf[nt], acc[mt][nt]);

    {
      const unsigned short* vp = kvh + (rowQ + lane) * 1024 + 512 + h * 32;
      u16x8 v0 = *(const u16x8*)(vp);
      u16x8 v1 = *(const u16x8*)(vp + 8);
      u16x8 v2 = *(const u16x8*)(vp + 16);
      u16x8 v3 = *(const u16x8*)(vp + 24);
#pragma unroll
      for (int j = 0; j < 8; ++j) {
        Vt[wave][j][lane]      = v0[j];
        Vt[wave][8 + j][lane]  = v1[j];
        Vt[wave][16 + j][lane] = v2[j];
        Vt[wave][24 + j][lane] = v3[j];
      }
    }

    float pden[4][4];
#pragma unroll
    for (int mt = 0; mt < 4; ++mt) {
#pragma unroll
      for (int r = 0; r < 4; ++r) {
        const int qrow = mt * 16 + lg * 4 + r;
        const float* rp = rpb + h * 4096 + qrow * 64 + lc;
        const float* mp = mask + w * 4096 + qrow * 64 + lc;
        float sc[4];
#pragma unroll
        for (int nt = 0; nt < 4; ++nt)
          sc[nt] = acc[mt][nt][r] * SCALEF + rp[nt * 16] + mp[nt * 16];
        float mx = fmaxf(fmaxf(sc[0], sc[1]), fmaxf(sc[2], sc[3]));
        mx = fmaxf(mx, __shfl_xor(mx, 1));
        mx = fmaxf(mx, __shfl_xor(mx, 2));
        mx = fmaxf(mx, __shfl_xor(mx, 4));
        mx = fmaxf(mx, __shfl_xor(mx, 8));
        float s = 0.f;
#pragma unroll
        for (int nt = 0; nt < 4; ++nt) { sc[nt] = __expf(sc[nt] - mx); s += sc[nt]; }
        s += __shfl_xor(s, 1);
        s += __shfl_xor(s, 2);
        s += __shfl_xor(s, 4);
        s += __shfl_xor(s, 8);
        pden[mt][r] = 1.f / s;
#pragma unroll
        for (int nt = 0; nt < 4; ++nt)
          P[wave][qrow][nt * 16 + lc] = f2bf(sc[nt]);
      }
    }

    f32x4 xacc[4][2];
#pragma unroll
    for (int mt = 0; mt < 4; ++mt)
#pragma unroll
      for (int nt = 0; nt < 2; ++nt)
        xacc[mt][nt] = f32x4{0.f, 0.f, 0.f, 0.f};
#pragma unroll
    for (int ks = 0; ks < 2; ++ks) {
      bf16x8 pa[4], vb[2];
#pragma unroll
      for (int mt = 0; mt < 4; ++mt)
        pa[mt] = *(const bf16x8*)&P[wave][mt * 16 + lc][ks * 32 + lg * 8];
#pragma unroll
      for (int nt = 0; nt < 2; ++nt)
        vb[nt] = *(const bf16x8*)&Vt[wave][nt * 16 + lc][ks * 32 + lg * 8];
#pragma unroll
      for (int mt = 0; mt < 4; ++mt)
#pragma unroll
        for (int nt = 0; nt < 2; ++nt)
          xacc[mt][nt] = MFMA16(pa[mt], vb[nt], xacc[mt][nt]);
    }

#pragma unroll
    for (int mt = 0; mt < 4; ++mt)
#pragma unroll
      for (int nt = 0; nt < 2; ++nt)
#pragma unroll
        for (int r = 0; r < 4; ++r) {
          const int qrow = mt * 16 + lg * 4 + r;
          x[(rowQ + qrow) * 512 + h * 32 + nt * 16 + lc] =
              f2bf(xacc[mt][nt][r] * pden[mt][r]);
        }
  }
}

extern "C" void kernel_launch(void* const* d_in, const int* in_sizes, int n_in,
                              void* d_out, int out_size, void* d_ws, size_t ws_size,
                              hipStream_t stream) {
  const float* q    = (const float*)d_in[0];
  const float* kv   = (const float*)d_in[1];
  const float* mask = (const float*)d_in[2];
  const float* Wq   = (const float*)d_in[3];
  const float* bq   = (const float*)d_in[4];
  const float* Wkv  = (const float*)d_in[5];
  const float* bkv  = (const float*)d_in[6];
  const float* btab = (const float*)d_in[7];
  const float* Wp   = (const float*)d_in[8];
  const float* bp   = (const float*)d_in[9];
  float* out = (float*)d_out;

  const int M = 4096 * 64;  // 262144 rows

  char* ws = (char*)d_ws;
  const size_t OFF_QH  = 0;
  const size_t OFF_KVH = OFF_QH + (size_t)M * 512 * 2;
  const size_t OFF_X   = OFF_KVH + (size_t)M * 1024 * 2;
  const size_t OFF_WQT = OFF_X + (size_t)M * 512 * 2;
  const size_t OFF_WKVT = OFF_WQT + 512 * 512 * 2;
  const size_t OFF_WPT  = OFF_WKVT + 1024 * 512 * 2;
  const size_t OFF_RPB  = OFF_WPT + 512 * 512 * 2;

  unsigned short* qh    = (unsigned short*)(ws + OFF_QH);
  unsigned short* kvh   = (unsigned short*)(ws + OFF_KVH);
  unsigned short* xb    = (unsigned short*)(ws + OFF_X);
  unsigned short* Wq_t  = (unsigned short*)(ws + OFF_WQT);
  unsigned short* Wkv_t = (unsigned short*)(ws + OFF_WKVT);
  unsigned short* Wp_t  = (unsigned short*)(ws + OFF_WPT);
  float* rpbf           = (float*)(ws + OFF_RPB);

  transpose_cvt_k<<<(512 * 512 + 255) / 256, 256, 0, stream>>>(Wq, Wq_t, 512, 512);
  transpose_cvt_k<<<(512 * 1024 + 255) / 256, 256, 0, stream>>>(Wkv, Wkv_t, 512, 1024);
  transpose_cvt_k<<<(512 * 512 + 255) / 256, 256, 0, stream>>>(Wp, Wp_t, 512, 512);
  build_rpb_k<<<(16 * 64 * 64 + 255) / 256, 256, 0, stream>>>(btab, rpbf);

  gemm_q_k<<<(M / 128) * (512 / 128), 256, 0, stream>>>(q, Wq_t, bq, qh, M, 512, 512);
  gemm_kv_k<<<(M / 128) * (1024 / 128), 256, 0, stream>>>(kv, Wkv_t, bkv, kvh, M, 1024, 512);

  attn_k<<<4096, 256, 0, stream>>>(qh, kvh, mask, rpbf, xb);

  gemm_out_k<<<(M / 128) * (512 / 128), 256, 0, stream>>>(xb, Wp_t, bp, out, M, 512, 512);

  (void)in_sizes; (void)n_in; (void)out_size; (void)ws_size;
}

// Round 5
// 1577.481 us; speedup vs baseline: 2.5304x; 1.6967x over previous
//
#include <hip/hip_runtime.h>

typedef short bf16x8 __attribute__((ext_vector_type(8)));
typedef unsigned short u16x8 __attribute__((ext_vector_type(8)));
typedef float f32x4 __attribute__((ext_vector_type(4)));

#define MFMA16(a, b, c) __builtin_amdgcn_mfma_f32_16x16x32_bf16((a), (b), (c), 0, 0, 0)

#define SCALEF 0.17677669529663687f  // 32^-0.5

__device__ __forceinline__ unsigned short f2bf(float f) {
  union { float f; unsigned u; } v; v.f = f;
  unsigned r = v.u + 0x7fffu + ((v.u >> 16) & 1u);  // RNE
  return (unsigned short)(r >> 16);
}

__device__ __forceinline__ void gl_lds16(const void* g, void* l) {
  __builtin_amdgcn_global_load_lds(
      (const __attribute__((address_space(1))) void*)g,
      (__attribute__((address_space(3))) void*)l, 16, 0, 0);
}

// ---------- prep kernels ----------
__global__ __launch_bounds__(256) void transpose_cvt_k(const float* __restrict__ W,
    unsigned short* __restrict__ Wt, int K, int N) {
  int i = blockIdx.x * 256 + threadIdx.x;
  if (i >= N * K) return;
  int n = i / K, k = i - n * K;
  Wt[i] = f2bf(W[(long)k * N + n]);
}

__global__ __launch_bounds__(256) void build_rpb_k(const float* __restrict__ bt,
    float* __restrict__ rpb) {
  int i = blockIdx.x * 256 + threadIdx.x;
  if (i >= 16 * 64 * 64) return;
  int h = i >> 12, q = (i >> 6) & 63, k = i & 63;
  int dh = (q >> 3) - (k >> 3) + 7;
  int dw = (q & 7) - (k & 7) + 7;
  rpb[i] = bt[(dh * 15 + dw) * 16 + h];
}

// fp32 -> bf16 bulk convert, 8 elems/thread (32B read, 16B write)
__global__ __launch_bounds__(256) void cvt_bf16_k(const float* __restrict__ in,
    unsigned short* __restrict__ out, int n8) {
  int i = blockIdx.x * 256 + threadIdx.x;
  if (i >= n8) return;
  const float4* p = (const float4*)(in + (size_t)i * 8);
  float4 a = p[0], b = p[1];
  uint4 pk;
  pk.x = (unsigned)f2bf(a.x) | ((unsigned)f2bf(a.y) << 16);
  pk.y = (unsigned)f2bf(a.z) | ((unsigned)f2bf(a.w) << 16);
  pk.z = (unsigned)f2bf(b.x) | ((unsigned)f2bf(b.y) << 16);
  pk.w = (unsigned)f2bf(b.z) | ((unsigned)f2bf(b.w) << 16);
  *(uint4*)(out + (size_t)i * 8) = pk;
}

// ---------- GEMM body: C[M,N] = A[M,K] @ Bt[N,K]^T + bias (all-bf16 m97) ----
// 128x128 tile, BK=64, 256 threads (4 waves 2x2), XCD-swizzled blockIdx.
// A and B both stream via global_load_lds width=16 into XOR-swizzled LDS
// (linear LDS dest + pre-swizzled per-lane global source; same XOR on read).
template <typename OT>
__device__ __forceinline__ void gemm_body(const unsigned short* __restrict__ A,
    const unsigned short* __restrict__ Bt, const float* __restrict__ bias,
    OT* __restrict__ C, int M, int N, int K)
{
  constexpr bool O_F32 = (sizeof(OT) == 4);

  __shared__ __align__(16) char smem[32768];
  unsigned short* Asm = (unsigned short*)smem;   // [128][64] swizzled, 16 KB
  unsigned short* Bsm = Asm + 8192;              // [128][64] swizzled, 16 KB

  const int tn = N >> 7;
  const int nbm = M >> 7;                        // 2048, divisible by 8
  const int g = blockIdx.x;
  const int xcd = g & 7;                         // hw XCD = blockIdx % 8
  const int s = g >> 3;
  const int bm = xcd * (nbm >> 3) + (s / tn);    // A-panel sharers on one XCD
  const int bn = s - (s / tn) * tn;

  const int tid = threadIdx.x;
  const int wave = tid >> 6, lane = tid & 63;
  const int wr = wave >> 1, wc = wave & 1;
  const int lg = lane >> 4, lc = lane & 15;

  const long rowBase = (long)bm * 128;
  const int colBase = bn * 128;
  const int KT = K >> 6;

  f32x4 acc[4][4];
#pragma unroll
  for (int i = 0; i < 4; ++i)
#pragma unroll
    for (int j = 0; j < 4; ++j)
      acc[i][j] = f32x4{0.f, 0.f, 0.f, 0.f};

  // staging lane geometry: each issue = 16B/lane, wave covers 8 rows x 128B
  const int blr = lane >> 3;                     // row-in-8
  const int bsw = (lane & 7) ^ blr;              // pre-swizzled source chunk

  auto issueA = [&](int kt) {
#pragma unroll
    for (int j = 0; j < 4; ++j) {
      int r = j * 32 + wave * 8 + blr;
      gl_lds16(A + (rowBase + r) * (long)K + kt * 64 + bsw * 8,
               Asm + (j * 4 + wave) * 512);
    }
  };
  auto issueB = [&](int kt) {
#pragma unroll
    for (int j = 0; j < 4; ++j) {
      int r = j * 32 + wave * 8 + blr;
      gl_lds16(Bt + (long)(colBase + r) * K + kt * 64 + bsw * 8,
               Bsm + (j * 4 + wave) * 512);
    }
  };
  auto compute = [&]() {
#pragma unroll
    for (int ks = 0; ks < 2; ++ks) {
      const int ca = (ks * 4 + lg) ^ (lc & 7);   // swizzled read chunk
      bf16x8 af[4], bfr[4];
#pragma unroll
      for (int mt = 0; mt < 4; ++mt)
        af[mt] = *(const bf16x8*)(Asm + (wr * 64 + mt * 16 + lc) * 64 + ca * 8);
#pragma unroll
      for (int nt = 0; nt < 4; ++nt)
        bfr[nt] = *(const bf16x8*)(Bsm + (wc * 64 + nt * 16 + lc) * 64 + ca * 8);
#pragma unroll
      for (int mt = 0; mt < 4; ++mt)
#pragma unroll
        for (int nt = 0; nt < 4; ++nt)
          acc[mt][nt] = MFMA16(af[mt], bfr[nt], acc[mt][nt]);
    }
  };

  issueA(0); issueB(0);
  __syncthreads();

  for (int kt = 0; kt < KT; ++kt) {
    const bool more = (kt + 1 < KT);
    compute();
    __syncthreads();
    if (more) {
      issueA(kt + 1); issueB(kt + 1);
      __syncthreads();
    }
  }

  // epilogue: bias + LDS-staged contiguous stores (reuse tile LDS, 64-row halves)
  float bv[4];
#pragma unroll
  for (int nt = 0; nt < 4; ++nt)
    bv[nt] = bias[colBase + wc * 64 + nt * 16 + lc];

  if constexpr (O_F32) {
    float* Sf = (float*)smem;                    // [64][128] f32
#pragma unroll
    for (int h = 0; h < 2; ++h) {
      if (wr == h) {
#pragma unroll
        for (int mt = 0; mt < 4; ++mt)
#pragma unroll
          for (int nt = 0; nt < 4; ++nt)
#pragma unroll
            for (int r = 0; r < 4; ++r)
              Sf[(mt * 16 + lg * 4 + r) * 128 + wc * 64 + nt * 16 + lc] =
                  acc[mt][nt][r] + bv[nt];
      }
      __syncthreads();
#pragma unroll
      for (int p = 0; p < 8; ++p) {
        int ch = p * 256 + tid, row = ch >> 5, c = ch & 31;
        *(float4*)((float*)C + (rowBase + h * 64 + row) * N + colBase + c * 4) =
            *(const float4*)(Sf + row * 128 + c * 4);
      }
      __syncthreads();
    }
  } else {
    unsigned short* Su = (unsigned short*)smem;  // [64][128] bf16
#pragma unroll
    for (int h = 0; h < 2; ++h) {
      if (wr == h) {
#pragma unroll
        for (int mt = 0; mt < 4; ++mt)
#pragma unroll
          for (int nt = 0; nt < 4; ++nt)
#pragma unroll
            for (int r = 0; r < 4; ++r)
              Su[(mt * 16 + lg * 4 + r) * 128 + wc * 64 + nt * 16 + lc] =
                  f2bf(acc[mt][nt][r] + bv[nt]);
      }
      __syncthreads();
#pragma unroll
      for (int p = 0; p < 4; ++p) {
        int ch = p * 256 + tid, row = ch >> 4, c = ch & 15;
        *(uint4*)((unsigned short*)C + (rowBase + h * 64 + row) * N + colBase + c * 8) =
            *(const uint4*)(Su + row * 128 + c * 8);
      }
      __syncthreads();
    }
  }
}

__global__ __launch_bounds__(256, 4) void gemm_q_k(const unsigned short* __restrict__ A,
    const unsigned short* __restrict__ Bt, const float* __restrict__ bias,
    unsigned short* __restrict__ C, int M, int N, int K) {
  gemm_body<unsigned short>(A, Bt, bias, C, M, N, K);
}
__global__ __launch_bounds__(256, 4) void gemm_kv_k(const unsigned short* __restrict__ A,
    const unsigned short* __restrict__ Bt, const float* __restrict__ bias,
    unsigned short* __restrict__ C, int M, int N, int K) {
  gemm_body<unsigned short>(A, Bt, bias, C, M, N, K);
}
__global__ __launch_bounds__(256, 4) void gemm_out_k(const unsigned short* __restrict__ A,
    const unsigned short* __restrict__ Bt, const float* __restrict__ bias,
    float* __restrict__ C, int M, int N, int K) {
  gemm_body<float>(A, Bt, bias, C, M, N, K);
}

// ---------- fused window attention ----------
// grid = 4096 windows, 4 waves; wave w handles heads 4w..4w+3.
// P/Vt are wave-private LDS -> no block barriers (wave-internal lgkmcnt).
__global__ __launch_bounds__(256) void attn_k(
    const unsigned short* __restrict__ qh,   // [B*64][512] bf16
    const unsigned short* __restrict__ kvh,  // [B*64][1024] bf16 (k | v)
    const float* __restrict__ mask,          // [64][64][64]
    const float* __restrict__ rpb,           // [16][64][64]
    unsigned short* __restrict__ x)          // [B*64][512] bf16
{
  __shared__ unsigned short P[4][64][72];
  __shared__ unsigned short Vt[4][32][72];

  const int b = blockIdx.x;
  const int w = b & 63;
  const int tid = threadIdx.x;
  const int wave = tid >> 6, lane = tid & 63;
  const int lg = lane >> 4, lc = lane & 15;
  const long rowQ = (long)b * 64;

  for (int hi = 0; hi < 4; ++hi) {
    const int h = wave * 4 + hi;

    bf16x8 qf[4], kf[4];
#pragma unroll
    for (int mt = 0; mt < 4; ++mt)
      qf[mt] = *(const bf16x8*)(qh + (rowQ + mt * 16 + lc) * 512 + h * 32 + lg * 8);
#pragma unroll
    for (int nt = 0; nt < 4; ++nt)
      kf[nt] = *(const bf16x8*)(kvh + (rowQ + nt * 16 + lc) * 1024 + h * 32 + lg * 8);

    f32x4 acc[4][4];
#pragma unroll
    for (int mt = 0; mt < 4; ++mt)
#pragma unroll
      for (int nt = 0; nt < 4; ++nt)
        acc[mt][nt] = f32x4{0.f, 0.f, 0.f, 0.f};
#pragma unroll
    for (int mt = 0; mt < 4; ++mt)
#pragma unroll
      for (int nt = 0; nt < 4; ++nt)
        acc[mt][nt] = MFMA16(qf[mt], kf[nt], acc[mt][nt]);

    {
      const unsigned short* vp = kvh + (rowQ + lane) * 1024 + 512 + h * 32;
      u16x8 v0 = *(const u16x8*)(vp);
      u16x8 v1 = *(const u16x8*)(vp + 8);
      u16x8 v2 = *(const u16x8*)(vp + 16);
      u16x8 v3 = *(const u16x8*)(vp + 24);
#pragma unroll
      for (int j = 0; j < 8; ++j) {
        Vt[wave][j][lane]      = v0[j];
        Vt[wave][8 + j][lane]  = v1[j];
        Vt[wave][16 + j][lane] = v2[j];
        Vt[wave][24 + j][lane] = v3[j];
      }
    }

    float pden[4][4];
#pragma unroll
    for (int mt = 0; mt < 4; ++mt) {
#pragma unroll
      for (int r = 0; r < 4; ++r) {
        const int qrow = mt * 16 + lg * 4 + r;
        const float* rp = rpb + h * 4096 + qrow * 64 + lc;
        const float* mp = mask + w * 4096 + qrow * 64 + lc;
        float sc[4];
#pragma unroll
        for (int nt = 0; nt < 4; ++nt)
          sc[nt] = acc[mt][nt][r] * SCALEF + rp[nt * 16] + mp[nt * 16];
        float mx = fmaxf(fmaxf(sc[0], sc[1]), fmaxf(sc[2], sc[3]));
        mx = fmaxf(mx, __shfl_xor(mx, 1));
        mx = fmaxf(mx, __shfl_xor(mx, 2));
        mx = fmaxf(mx, __shfl_xor(mx, 4));
        mx = fmaxf(mx, __shfl_xor(mx, 8));
        float s = 0.f;
#pragma unroll
        for (int nt = 0; nt < 4; ++nt) { sc[nt] = __expf(sc[nt] - mx); s += sc[nt]; }
        s += __shfl_xor(s, 1);
        s += __shfl_xor(s, 2);
        s += __shfl_xor(s, 4);
        s += __shfl_xor(s, 8);
        pden[mt][r] = 1.f / s;
#pragma unroll
        for (int nt = 0; nt < 4; ++nt)
          P[wave][qrow][nt * 16 + lc] = f2bf(sc[nt]);
      }
    }

    f32x4 xacc[4][2];
#pragma unroll
    for (int mt = 0; mt < 4; ++mt)
#pragma unroll
      for (int nt = 0; nt < 2; ++nt)
        xacc[mt][nt] = f32x4{0.f, 0.f, 0.f, 0.f};
#pragma unroll
    for (int ks = 0; ks < 2; ++ks) {
      bf16x8 pa[4], vb[2];
#pragma unroll
      for (int mt = 0; mt < 4; ++mt)
        pa[mt] = *(const bf16x8*)&P[wave][mt * 16 + lc][ks * 32 + lg * 8];
#pragma unroll
      for (int nt = 0; nt < 2; ++nt)
        vb[nt] = *(const bf16x8*)&Vt[wave][nt * 16 + lc][ks * 32 + lg * 8];
#pragma unroll
      for (int mt = 0; mt < 4; ++mt)
#pragma unroll
        for (int nt = 0; nt < 2; ++nt)
          xacc[mt][nt] = MFMA16(pa[mt], vb[nt], xacc[mt][nt]);
    }

#pragma unroll
    for (int mt = 0; mt < 4; ++mt)
#pragma unroll
      for (int nt = 0; nt < 2; ++nt)
#pragma unroll
        for (int r = 0; r < 4; ++r) {
          const int qrow = mt * 16 + lg * 4 + r;
          x[(rowQ + qrow) * 512 + h * 32 + nt * 16 + lc] =
              f2bf(xacc[mt][nt][r] * pden[mt][r]);
        }
  }
}

extern "C" void kernel_launch(void* const* d_in, const int* in_sizes, int n_in,
                              void* d_out, int out_size, void* d_ws, size_t ws_size,
                              hipStream_t stream) {
  const float* q    = (const float*)d_in[0];
  const float* kv   = (const float*)d_in[1];
  const float* mask = (const float*)d_in[2];
  const float* Wq   = (const float*)d_in[3];
  const float* bq   = (const float*)d_in[4];
  const float* Wkv  = (const float*)d_in[5];
  const float* bkv  = (const float*)d_in[6];
  const float* btab = (const float*)d_in[7];
  const float* Wp   = (const float*)d_in[8];
  const float* bp   = (const float*)d_in[9];
  float* out = (float*)d_out;

  const int M = 4096 * 64;  // 262144 rows

  char* ws = (char*)d_ws;
  // Layout (~1.03 GB): qh | kvh | scratch(kvbf -> qbf -> xb, time-shared) | weights
  const size_t OFF_QH   = 0;                               // 256 MB
  const size_t OFF_KVH  = OFF_QH + (size_t)M * 512 * 2;    // 512 MB
  const size_t OFF_SCR  = OFF_KVH + (size_t)M * 1024 * 2;  // 256 MB (time-shared)
  const size_t OFF_WQT  = OFF_SCR + (size_t)M * 512 * 2;
  const size_t OFF_WKVT = OFF_WQT + 512 * 512 * 2;
  const size_t OFF_WPT  = OFF_WKVT + 1024 * 512 * 2;
  const size_t OFF_RPB  = OFF_WPT + 512 * 512 * 2;

  unsigned short* qh    = (unsigned short*)(ws + OFF_QH);
  unsigned short* kvh   = (unsigned short*)(ws + OFF_KVH);
  unsigned short* scr   = (unsigned short*)(ws + OFF_SCR); // kvbf / qbf / xb
  unsigned short* Wq_t  = (unsigned short*)(ws + OFF_WQT);
  unsigned short* Wkv_t = (unsigned short*)(ws + OFF_WKVT);
  unsigned short* Wp_t  = (unsigned short*)(ws + OFF_WPT);
  float* rpbf           = (float*)(ws + OFF_RPB);

  transpose_cvt_k<<<(512 * 512 + 255) / 256, 256, 0, stream>>>(Wq, Wq_t, 512, 512);
  transpose_cvt_k<<<(512 * 1024 + 255) / 256, 256, 0, stream>>>(Wkv, Wkv_t, 512, 1024);
  transpose_cvt_k<<<(512 * 512 + 255) / 256, 256, 0, stream>>>(Wp, Wp_t, 512, 512);
  build_rpb_k<<<(16 * 64 * 64 + 255) / 256, 256, 0, stream>>>(btab, rpbf);

  const int n8 = M * 512 / 8;  // 16M chunks of 8 floats

  // kv -> bf16 -> KV-proj (scratch holds kvbf)
  cvt_bf16_k<<<n8 / 256, 256, 0, stream>>>(kv, scr, n8);
  gemm_kv_k<<<(M / 128) * (1024 / 128), 256, 0, stream>>>(scr, Wkv_t, bkv, kvh, M, 1024, 512);

  // q -> bf16 -> Q-proj (scratch reused for qbf)
  cvt_bf16_k<<<n8 / 256, 256, 0, stream>>>(q, scr, n8);
  gemm_q_k<<<(M / 128) * (512 / 128), 256, 0, stream>>>(scr, Wq_t, bq, qh, M, 512, 512);

  // attention (scratch reused for xb)
  attn_k<<<4096, 256, 0, stream>>>(qh, kvh, mask, rpbf, scr);

  gemm_out_k<<<(M / 128) * (512 / 128), 256, 0, stream>>>(scr, Wp_t, bp, out, M, 512, 512);

  (void)in_sizes; (void)n_in; (void)out_size; (void)ws_size;
}